// Round 12
// baseline (235.059 us; speedup 1.0000x reference)
//
#include <hip/hip_runtime.h>

// Inverse wavelet transform (Haar):
//   x: [4B, C, H, W] fp32, B=8, C=64, H=128, W=128 -> out: [B, C, 2H, 2W]
//
// Round-12 (= round-11 resubmitted after broker timeout): TRUE async deep
// prefetch via __builtin_amdgcn_global_load_lds + counted vmcnt.
// r2/r4/r7/r8/r10 (sync VGPR loads in every flavor) all pinned at 79-88us /
// 2.5 TB/s with HBM ~60% idle, VALU ~5%, 0 conflicts -> latency-bound with
// capped per-wave outstanding requests. r7's VGPR_Count=32 proved the
// compiler re-serializes sync load batches. global_load_lds writes no VGPRs
// -> genuinely fire-and-forget; a wave holds 16 KB (16 x 1KB chunks) in
// flight, ordered only by explicit counted s_waitcnt vmcnt(N) (T4).
//
// 1 wave/block (64 thr), 8192 blocks. Block = 8-row strip of one channel:
//   prologue: 16 async 1KB loads (4 row-pairs x 4 quarters) -> 16 KB LDS
//   drain:    pair p waits vmcnt(12-4p) (later pairs stay in flight),
//             computes, NT-stores 4 output rows (1 KB contiguous each).

typedef float f2 __attribute__((ext_vector_type(2)));
typedef float f4 __attribute__((ext_vector_type(4)));

constexpr int H = 128, W = 128;
constexpr int HW = H * W;          // 16384 floats per (b,c) input plane
constexpr int OUT_ROW = 2 * W;     // 256 floats per output row
constexpr int OUT_PLANE = 4 * HW;  // 65536 floats per (b,c) output plane

__global__ __launch_bounds__(64) void iwt_kernel(const float* __restrict__ x,
                                                 float* __restrict__ out,
                                                 int quarter)
{
    __shared__ float lds[16 * 256];   // 16 KB: [pair 0..3][quarter 0..3][2 rows x 128]

    const int lane = threadIdx.x;          // 0..63
    const int cb   = blockIdx.x >> 4;      // b*C + c, 0..511
    const int r0   = (blockIdx.x & 15) << 3;   // strip base input row (8 rows)

    // Lane-l global source for a 1KB chunk: base + lane*16B (global_load_lds
    // writes LDS at wave-uniform base + lane*size -> linear layout).
    const float* xbase = x + cb * HW + r0 * W + (lane << 2);

    // ---- Prologue: fire all 16 async global->LDS loads (16 KB in flight) ----
#pragma unroll
    for (int p = 0; p < 4; ++p) {
#pragma unroll
        for (int q = 0; q < 4; ++q) {
            const float* src = xbase + q * quarter + (p * 2) * W;
            __builtin_amdgcn_global_load_lds(
                (const __attribute__((address_space(1))) void*)src,
                (__attribute__((address_space(3))) void*)&lds[(p * 4 + q) * 256],
                16, 0, 0);
        }
    }

    float* obase = out + cb * OUT_PLANE + (lane << 2);

    // ---- Drain: counted vmcnt, never waiting on loads we don't need yet ----
#pragma unroll
    for (int p = 0; p < 4; ++p) {
        if      (p == 0) asm volatile("s_waitcnt vmcnt(12)" ::: "memory");
        else if (p == 1) asm volatile("s_waitcnt vmcnt(8)"  ::: "memory");
        else if (p == 2) asm volatile("s_waitcnt vmcnt(4)"  ::: "memory");
        else             asm volatile("s_waitcnt vmcnt(0)"  ::: "memory");

        const float* lp = &lds[p * 1024];

#pragma unroll
        for (int ii = 0; ii < 2; ++ii) {
            // lane l handles input cols (2l, 2l+1) of input row r0+2p+ii.
            f2 v1 = *reinterpret_cast<const f2*>(lp + 0 * 256 + ii * 128 + (lane << 1));
            f2 v2 = *reinterpret_cast<const f2*>(lp + 1 * 256 + ii * 128 + (lane << 1));
            f2 v3 = *reinterpret_cast<const f2*>(lp + 2 * 256 + ii * 128 + (lane << 1));
            f2 v4 = *reinterpret_cast<const f2*>(lp + 3 * 256 + ii * 128 + (lane << 1));

            float a1 = v1[0] * 0.5f, a2 = v2[0] * 0.5f, a3 = v3[0] * 0.5f, a4 = v4[0] * 0.5f;
            float b1 = v1[1] * 0.5f, b2 = v2[1] * 0.5f, b3 = v3[1] * 0.5f, b4 = v4[1] * 0.5f;

            f4 oe = { a1 - a2 - a3 + a4, a1 + a2 - a3 - a4,    // e00, e01 (cols 4l..)
                      b1 - b2 - b3 + b4, b1 + b2 - b3 - b4 };
            f4 oo = { a1 - a2 + a3 - a4, a1 + a2 + a3 + a4,    // e10, e11
                      b1 - b2 + b3 - b4, b1 + b2 + b3 + b4 };

            const int orow = 2 * (r0 + 2 * p + ii);
            __builtin_nontemporal_store(oe, reinterpret_cast<f4*>(obase + orow * OUT_ROW));
            __builtin_nontemporal_store(oo, reinterpret_cast<f4*>(obase + (orow + 1) * OUT_ROW));
        }
    }
}

extern "C" void kernel_launch(void* const* d_in, const int* in_sizes, int n_in,
                              void* d_out, int out_size, void* d_ws, size_t ws_size,
                              hipStream_t stream) {
    const float* x = (const float*)d_in[0];
    float* out = (float*)d_out;

    const int quarter = in_sizes[0] / 4;        // 8,388,608
    const int n_cb    = quarter / HW;           // 512 channels
    const int grid    = n_cb * (H / 8);         // 512 * 16 = 8192 blocks
    const int block   = 64;                     // 1 wave

    iwt_kernel<<<grid, block, 0, stream>>>(x, out, quarter);
}